// Round 1
// baseline (361.113 us; speedup 1.0000x reference)
//
#include <hip/hip_runtime.h>

#define J 2048
#define BATCH 32768

typedef float vfloat4 __attribute__((ext_vector_type(4)));

// 512 threads = 8 waves/block, grid 1024 -> 8192 waves = 32 waves/CU (full slots).
// LDS: sp = P/(2pi) (8 KB), sw0/sw1 = de-interleaved W columns (8 KB each) = 24 KB/block;
// 4 blocks/CU x 24 KB = 96 KB <= 160 KB, so LDS does not cap occupancy.
// Loop VMEM = ONLY the x stream: 1 KB per wave-instruction (4 rows x 256 B contiguous).
// P/W reads moved to ds_read_b128 with 2-way bank aliasing (free per m136).
__global__ __launch_bounds__(512)
void QuantumEmbedding_50964081935097_kernel(const float* __restrict__ x,
                                            const float* __restrict__ W,   // [J,2]
                                            const float* __restrict__ P,   // [J]
                                            float* __restrict__ out)       // [BATCH,2]
{
    __shared__ float sp[J];    // P * inv2pi
    __shared__ float sw0[J];   // W[:,0]
    __shared__ float sw1[J];   // W[:,1]

    const int tid = threadIdx.x;
    const float inv2pi = 0.15915494309189535f;

    // One-time cooperative stage: 512 threads x (1 P-float4 + 2 W-float4).
    {
        vfloat4 pv = reinterpret_cast<const vfloat4*>(P)[tid];
        pv.x *= inv2pi; pv.y *= inv2pi; pv.z *= inv2pi; pv.w *= inv2pi;
        reinterpret_cast<vfloat4*>(sp)[tid] = pv;

        vfloat4 wa = reinterpret_cast<const vfloat4*>(W)[tid];        // rows 2t,2t+1
        vfloat4 wb = reinterpret_cast<const vfloat4*>(W)[tid + 512];  // rows 2t+1024,...
        *reinterpret_cast<float2*>(sw0 + 2 * tid)        = make_float2(wa.x, wa.z);
        *reinterpret_cast<float2*>(sw1 + 2 * tid)        = make_float2(wa.y, wa.w);
        *reinterpret_cast<float2*>(sw0 + 2 * tid + 1024) = make_float2(wb.x, wb.z);
        *reinterpret_cast<float2*>(sw1 + 2 * tid + 1024) = make_float2(wb.y, wb.w);
    }
    __syncthreads();

    const int lane = tid & 63;
    const int wave = blockIdx.x * 8 + (tid >> 6);
    const int r = lane & 3;        // row within 4-row group
    const int t = lane >> 2;       // column-chunk index, 0..15
    const int base_row = wave * 4;

    // plain (cache-allocating) loads: x is exactly L3-sized; never refuse free hits
    const float* xr = x + (size_t)(base_row + r) * J;

    float acc0 = 0.f, acc1 = 0.f;

#pragma unroll 4
    for (int k = 0; k < 32; ++k) {
        const int col = k * 64 + t * 4;
        vfloat4 xv = *reinterpret_cast<const vfloat4*>(xr + col);
        vfloat4 pv = *reinterpret_cast<const vfloat4*>(sp + col);
        vfloat4 w0 = *reinterpret_cast<const vfloat4*>(sw0 + col);
        vfloat4 w1 = *reinterpret_cast<const vfloat4*>(sw1 + col);

        // v_cos_f32 takes revolutions; the 1/2pi is pre-folded into sp
        float c0 = __builtin_amdgcn_cosf(xv.x * pv.x);
        float c1 = __builtin_amdgcn_cosf(xv.y * pv.y);
        float c2 = __builtin_amdgcn_cosf(xv.z * pv.z);
        float c3 = __builtin_amdgcn_cosf(xv.w * pv.w);

        acc0 += c0 * w0.x + c1 * w0.y + c2 * w0.z + c3 * w0.w;
        acc1 += c0 * w1.x + c1 * w1.y + c2 * w1.z + c3 * w1.w;
    }

    // reduce across t (16 lanes per row, stride 4): 4-step butterfly
    acc0 += __shfl_down(acc0, 32, 64);
    acc1 += __shfl_down(acc1, 32, 64);
    acc0 += __shfl_down(acc0, 16, 64);
    acc1 += __shfl_down(acc1, 16, 64);
    acc0 += __shfl_down(acc0, 8, 64);
    acc1 += __shfl_down(acc1, 8, 64);
    acc0 += __shfl_down(acc0, 4, 64);
    acc1 += __shfl_down(acc1, 4, 64);

    if (lane < 4) {
        // lanes 0..3 hold rows base_row+0..3 -> 32 B contiguous store
        *reinterpret_cast<float2*>(out + (size_t)(base_row + lane) * 2) =
            make_float2(acc0, acc1);
    }
}

extern "C" void kernel_launch(void* const* d_in, const int* in_sizes, int n_in,
                              void* d_out, int out_size, void* d_ws, size_t ws_size,
                              hipStream_t stream) {
    const float* x = (const float*)d_in[0];
    const float* W = (const float*)d_in[1];
    const float* P = (const float*)d_in[2];
    float* out = (float*)d_out;

    // 32768 rows / 4 rows-per-wave = 8192 waves = 1024 blocks x 8 waves
    dim3 grid(1024), block(512);
    hipLaunchKernelGGL(QuantumEmbedding_50964081935097_kernel, grid, block, 0, stream,
                       x, W, P, out);
}